// Round 1
// 285.748 us; speedup vs baseline: 1.0465x; 1.0465x over previous
//
#include <hip/hip_runtime.h>
#include <stdint.h>
#include <stddef.h>

// MASLoRALinear via concatenation identity:
//   hg[b,t,e*16+r] = SCALING * w[b,e] * (x @ As^T)[b,t,e,r]      (gate baked in)
//   out = [x_bf16 | hg] @ [W_base | Bcat]^T + b_base
// Round 4: (a) main_gemm BK 32->64 (18 K-steps, 36 barrier drains instead of 72;
// m97-ladder config) with 8-chunk XOR swizzle for conflict-free b128 reads;
// (b) cvt_h re-tiled to 32 rows x 750 blocks (fixes 375-block makespan: 2T -> 1.5T)
// and BK=64. XCD-affine map in main_gemm kept.

#define B_ 16
#define T_ 1500
#define C_ 1024
#define O_ 1024
#define E_ 8
#define R_ 16
#define ER 128     // E*R
#define KK 1152    // C_ + ER
#define BT 24000   // B_*T_  (= 750 * 32 exactly)
#define SCALING 2.0f

typedef __bf16 bf16x8 __attribute__((ext_vector_type(8)));
typedef float f32x4 __attribute__((ext_vector_type(4)));
typedef unsigned short u16;

__device__ inline u16 f2bf(float f) {
  union { float f; unsigned u; } v; v.f = f;
  unsigned u = v.u;
  u += 0x7fff + ((u >> 16) & 1);  // RNE
  return (u16)(u >> 16);
}

#define GLL(gp, lp)                                                            \
  __builtin_amdgcn_global_load_lds(                                            \
      (const __attribute__((address_space(1))) void*)(gp),                     \
      (__attribute__((address_space(3))) void*)(lp), 16, 0, 0)

// ---------------- kernel 1: prep weights ----------------
// wp[o][0:1024]=bf16(W_base), wp[o][1024+e*16+r]=bf16(Bs[e,o,r]); ap=bf16(As flat).
__global__ __launch_bounds__(256) void prep_w(const float* __restrict__ Wb,
                                              const float* __restrict__ Bs,
                                              const float* __restrict__ As,
                                              u16* __restrict__ wp,
                                              u16* __restrict__ ap) {
  int idx = blockIdx.x * 256 + threadIdx.x;
  if (idx < O_ * KK) {
    int o = idx / KK;
    int k = idx - o * KK;
    float v;
    if (k < C_) {
      v = Wb[o * C_ + k];
    } else {
      int j = k - C_;
      v = Bs[((j >> 4) * O_ + o) * R_ + (j & 15)];
    }
    wp[idx] = f2bf(v);
  } else {
    int a = idx - O_ * KK;  // 131,072 elements of As
    ap[a] = f2bf(As[a]);
  }
}

// ---------------- kernel 2: fused convert + h-GEMM + gate ----------------
// Per 32-row M-tile (750 blocks -> ~3 resident blocks/CU, balanced makespan):
// stream x fp32, convert to bf16 in regs, ds_write into pad-72 LDS A
// (2-way=free frag reads) AND store to X'[:,0:1024]; MFMA vs Asb staged via
// GLL at BK=64 (8-chunk XOR swizzle); epilogue writes gated hg into
// X'[:,1024:1152]. Waves 2x2: each 16 rows x 64 cols (acc[4]).
__global__ __launch_bounds__(256) void cvt_h(const float* __restrict__ x,
                                             const u16* __restrict__ ab,
                                             const float* __restrict__ w,
                                             u16* __restrict__ xp) {
  const int mt = blockIdx.x;  // 0..749 (exact: 750*32 = 24000)
  const int tid = threadIdx.x, lane = tid & 63, wv = tid >> 6;
  const int wrow = wv & 1, wcol = wv >> 1, l15 = lane & 15, quad = lane >> 4;
  const int s7 = l15 & 7;

  __shared__ u16 lA[32 * 72];   // row stride 72 u16 = 144 B -> bank step 4 (2-way reads)
  __shared__ u16 lB[128 * 64];  // GLL-staged, 8-chunk XOR swizzle

  const size_t row0 = (size_t)mt * 32;

  f32x4 acc[4];
#pragma unroll
  for (int j = 0; j < 4; ++j) acc[j] = (f32x4){0.f, 0.f, 0.f, 0.f};

  // lB staging: 4 rounds of 256 threads; idx=c*256+tid; row=idx>>3; phys chunk
  // p=idx&7 holds logical chunk p^(row&7)  (read side XORs the same way).
  int brow[4], bko[4];
#pragma unroll
  for (int c = 0; c < 4; ++c) {
    int idx = c * 256 + tid;
    brow[c] = idx >> 3;
    bko[c] = (((idx & 7) ^ (brow[c] & 7)) << 3);
  }

  const int xr = tid >> 3;             // 0..31
  const int xc = (tid & 7) * 4;        // 0,4,..,28  (two col-halves: +0, +32)

  for (int kt = 0; kt < C_ / 64; ++kt) {  // 16 iterations
    const int k0 = kt * 64;
#pragma unroll
    for (int c = 0; c < 4; ++c)
      GLL(ab + brow[c] * C_ + k0 + bko[c], &lB[(c * 256 + tid) * 8]);
    float4 v0 = *(const float4*)&x[(row0 + xr) * C_ + k0 + xc];
    float4 v1 = *(const float4*)&x[(row0 + xr) * C_ + k0 + 32 + xc];
    ushort4 o0, o1;
    o0.x = f2bf(v0.x); o0.y = f2bf(v0.y); o0.z = f2bf(v0.z); o0.w = f2bf(v0.w);
    o1.x = f2bf(v1.x); o1.y = f2bf(v1.y); o1.z = f2bf(v1.z); o1.w = f2bf(v1.w);
    *(ushort4*)&lA[xr * 72 + xc] = o0;
    *(ushort4*)&lA[xr * 72 + 32 + xc] = o1;
    *(ushort4*)&xp[(row0 + xr) * KK + k0 + xc] = o0;
    *(ushort4*)&xp[(row0 + xr) * KK + k0 + 32 + xc] = o1;
    __syncthreads();  // drains GLL (vmcnt) + ds_writes (lgkmcnt)
#pragma unroll
    for (int kk = 0; kk < 2; ++kk) {
      bf16x8 af = *(const bf16x8*)&lA[(wrow * 16 + l15) * 72 + kk * 32 + quad * 8];
      bf16x8 bfr[4];
#pragma unroll
      for (int j = 0; j < 4; ++j)
        bfr[j] = *(const bf16x8*)&lB[(wcol * 64 + j * 16 + l15) * 64 +
                                     (((kk * 4 + quad) ^ s7) << 3)];
#pragma unroll
      for (int j = 0; j < 4; ++j)
        acc[j] = __builtin_amdgcn_mfma_f32_16x16x32_bf16(af, bfr[j], acc[j], 0, 0, 0);
    }
    __syncthreads();
  }

  // epilogue: col -> expert e = wcol*4+j (lane-uniform), rank r = l15
#pragma unroll
  for (int j = 0; j < 4; ++j) {
    const int col = wcol * 64 + j * 16 + l15;
    const int e = wcol * 4 + j;
#pragma unroll
    for (int rr = 0; rr < 4; ++rr) {
      const int row = mt * 32 + wrow * 16 + quad * 4 + rr;
      const int b = row / T_;
      xp[(size_t)row * KK + C_ + col] = f2bf(acc[j][rr] * (SCALING * w[b * E_ + e]));
    }
  }
}

// ---------------- kernel 3: main GEMM ----------------
// out[row][o] = X'[row,:] . W'[o,:] + b_base[o];  M=24000 K=1152 N=1024.
// BK=64: 18 K-steps, 36 barrier drains (was 72 at BK=32). 8-chunk XOR swizzle:
// phys chunk p of LDS row r holds logical chunk p^(r&7); frag read at logical
// chunk kk*4+quad XORs with l15&7 -> 2-way (free) bank aliasing on b128 reads.
// XCD-affine map: all 8 nt's of one mt share id%8 (same XCD, adjacent launch)
// -> A-tile fetched once per XCD; W' (2.3 MB) L2-resident per XCD.
__global__ __launch_bounds__(256) void main_gemm(const u16* __restrict__ xp,
                                                 const u16* __restrict__ wp,
                                                 const float* __restrict__ bb,
                                                 float* __restrict__ out) {
  const int id = blockIdx.x;                     // 0..1535
  const int mt = ((id >> 6) << 3) | (id & 7);    // 0..191
  const int nt = (id >> 3) & 7;                  // 0..7
  if (mt >= 188) return;                          // uniform early-exit (no barriers yet)
  const int tid = threadIdx.x, lane = tid & 63, wv = tid >> 6;
  const int wrow = wv & 1, wcol = wv >> 1, l15 = lane & 15, quad = lane >> 4;
  const int s7 = l15 & 7;

  __shared__ u16 lA[128 * 64];
  __shared__ u16 lB[128 * 64];
  const u16* gA = xp + (size_t)mt * 128 * KK;
  const u16* gB = wp + (size_t)nt * 128 * KK;

  f32x4 acc[4][4];
#pragma unroll
  for (int i = 0; i < 4; ++i)
#pragma unroll
    for (int j = 0; j < 4; ++j) acc[i][j] = (f32x4){0.f, 0.f, 0.f, 0.f};

  // staging: 4 rounds per matrix; idx=c*256+tid; row=idx>>3; 8-chunk XOR swizzle
  int srow[4], sko[4];
#pragma unroll
  for (int c = 0; c < 4; ++c) {
    int idx = c * 256 + tid;
    srow[c] = idx >> 3;
    sko[c] = (((idx & 7) ^ (srow[c] & 7)) << 3);
  }

  for (int kt = 0; kt < KK / 64; ++kt) {  // 18 iterations
    const int k0 = kt * 64;
#pragma unroll
    for (int c = 0; c < 4; ++c)
      GLL(gA + (size_t)srow[c] * KK + k0 + sko[c], &lA[(c * 256 + tid) * 8]);
#pragma unroll
    for (int c = 0; c < 4; ++c)
      GLL(gB + (size_t)srow[c] * KK + k0 + sko[c], &lB[(c * 256 + tid) * 8]);
    __syncthreads();
#pragma unroll
    for (int kk = 0; kk < 2; ++kk) {
      bf16x8 af[4], bfr[4];
#pragma unroll
      for (int i = 0; i < 4; ++i) {
        const int ko = (((kk * 4 + quad) ^ s7) << 3);
        af[i] = *(const bf16x8*)&lA[(wrow * 64 + i * 16 + l15) * 64 + ko];
        bfr[i] = *(const bf16x8*)&lB[(wcol * 64 + i * 16 + l15) * 64 + ko];
      }
#pragma unroll
      for (int i = 0; i < 4; ++i)
#pragma unroll
        for (int j = 0; j < 4; ++j)
          acc[i][j] = __builtin_amdgcn_mfma_f32_16x16x32_bf16(af[i], bfr[j], acc[i][j], 0, 0, 0);
    }
    __syncthreads();
  }

#pragma unroll
  for (int j = 0; j < 4; ++j) {
    const int col = nt * 128 + wcol * 64 + j * 16 + l15;
    const float bias = bb[col];
#pragma unroll
    for (int i = 0; i < 4; ++i) {
#pragma unroll
      for (int rr = 0; rr < 4; ++rr) {
        const int row = mt * 128 + wrow * 64 + i * 16 + quad * 4 + rr;
        if (row < BT) out[(size_t)row * O_ + col] = acc[i][j][rr] + bias;
      }
    }
  }
}

extern "C" void kernel_launch(void* const* d_in, const int* in_sizes, int n_in,
                              void* d_out, int out_size, void* d_ws, size_t ws_size,
                              hipStream_t stream) {
  const float* x = (const float*)d_in[0];    // (16,1500,1024)
  const float* w = (const float*)d_in[1];    // (16,8)
  const float* Wb = (const float*)d_in[2];   // (1024,1024)
  const float* bb = (const float*)d_in[3];   // (1024,)
  const float* As = (const float*)d_in[4];   // (8,16,1024)
  const float* Bs = (const float*)d_in[5];   // (8,1024,16)
  float* out = (float*)d_out;                // (16,1500,1024) fp32

  // ws: X' (24000x1152 u16, 55.30 MB) | W' (1024x1152 u16, 2.36 MB) | Asb (128x1024 u16, 0.26 MB)
  // main_gemm mt=187 staging over-reads rows 24000..24063 -> land in W' region (allocated, masked).
  u16* xp = (u16*)d_ws;
  u16* wp = xp + (size_t)BT * KK;
  u16* ap = wp + (size_t)O_ * KK;

  prep_w<<<(O_ * KK + ER * C_) / 256, 256, 0, stream>>>(Wb, Bs, As, wp, ap);
  cvt_h<<<750, 256, 0, stream>>>(x, ap, w, xp);
  main_gemm<<<1536, 256, 0, stream>>>(xp, wp, bb, out);
}